// Round 10
// baseline (853.510 us; speedup 1.0000x reference)
//
#include <hip/hip_runtime.h>
#include <cmath>

#define N_NODES 50000
#define N_EDGES 800000
#define IN_DIM 1024
#define HID 512
#define N_CLASSES 6
#define N_GRAPHS 8
#define NEG_SLOPE 0.2f
#define SCAN_BLK 256
#define N_SCAN_BLOCKS ((N_NODES + SCAN_BLK - 1) / SCAN_BLK)   // 196
#define POOL_STRIP 256
#define POOL_NBLOCKS ((N_NODES + POOL_STRIP - 1) / POOL_STRIP) // 196

typedef _Float16 half8 __attribute__((ext_vector_type(8)));
typedef _Float16 half4 __attribute__((ext_vector_type(4)));
typedef float floatx4 __attribute__((ext_vector_type(4)));

// ---------- async global->LDS, 16B per lane ----------
typedef const __attribute__((address_space(1))) void* gas_ptr;
typedef __attribute__((address_space(3))) void* las_ptr;
#define GLOAD16(gp, lp) \
    __builtin_amdgcn_global_load_lds((gas_ptr)(gp), (las_ptr)(lp), 16, 0, 0)

// ---------- x precast: f32 [N,1024] -> f16 ----------
__global__ __launch_bounds__(256) void cast_x_f16(const float* __restrict__ x,
                                                  _Float16* __restrict__ x16) {
    const size_t TOT = (size_t)N_NODES * IN_DIM;
    size_t i = ((size_t)blockIdx.x * blockDim.x + threadIdx.x) * 8;
    const size_t step = (size_t)gridDim.x * blockDim.x * 8;
    for (; i < TOT; i += step) {
        float4 f0 = *(const float4*)(x + i);
        float4 f1 = *(const float4*)(x + i + 4);
        half8 o;
        o[0] = (_Float16)f0.x; o[1] = (_Float16)f0.y;
        o[2] = (_Float16)f0.z; o[3] = (_Float16)f0.w;
        o[4] = (_Float16)f1.x; o[5] = (_Float16)f1.y;
        o[6] = (_Float16)f1.z; o[7] = (_Float16)f1.w;
        *(half8*)(x16 + i) = o;
    }
}

// ---------- all-3-layer W transpose + cast in one launch ----------
__global__ __launch_bounds__(256) void transpose_cast_W3(const float* __restrict__ W1,
                                                         const float* __restrict__ W2,
                                                         const float* __restrict__ W3,
                                                         _Float16* __restrict__ Wt1,
                                                         _Float16* __restrict__ Wt2,
                                                         _Float16* __restrict__ Wt3) {
    const int l = blockIdx.z;
    const float* W = (l == 0) ? W1 : (l == 1) ? W2 : W3;
    _Float16* Wt   = (l == 0) ? Wt1 : (l == 1) ? Wt2 : Wt3;
    const int K    = (l == 0) ? IN_DIM : HID;
    if (blockIdx.x * 32 >= K) return;
    __shared__ float sh[32][33];
    const int kb = blockIdx.x * 32, nb = blockIdx.y * 32;
    const int tx = threadIdx.x & 31, ty = threadIdx.x >> 5;
#pragma unroll
    for (int i = 0; i < 32; i += 8)
        sh[ty + i][tx] = W[(size_t)(kb + ty + i) * HID + nb + tx];
    __syncthreads();
#pragma unroll
    for (int i = 0; i < 32; i += 8)
        Wt[(size_t)(nb + ty + i) * K + kb + tx] = (_Float16)sh[tx][ty + i];
}

// ---------- MFMA GEMM + fused attention dots ----------
// 128x128 tile, 4 waves (2x2), BK=64, gload_lds + both-sides swizzle (rule 21).
// Epilogue additionally computes a_s[row] += h[row].att_s, a_d likewise, from
// the f32 acc fragments (shfl-reduce over the 16-lane fr group + atomicAdd;
// a_s/a_d zeroed before launch).
__global__ __launch_bounds__(256) void gemm_mfma_f16(const _Float16* __restrict__ A,
                                                     const _Float16* __restrict__ Bt,
                                                     _Float16* __restrict__ C,
                                                     const float* __restrict__ att_s,
                                                     const float* __restrict__ att_d,
                                                     float* __restrict__ a_s,
                                                     float* __restrict__ a_d,
                                                     int M, int K) {
    const int nwg = gridDim.x;
    const int bid = blockIdx.x;
    const int q = nwg >> 3, r = nwg & 7;
    const int xcd = bid & 7, local = bid >> 3;
    const int wgid = (xcd < r) ? xcd * (q + 1) + local
                               : r * (q + 1) + (xcd - r) * q + local;
    const int rowBase = (wgid >> 2) * 128;
    const int colBase = (wgid & 3) * 128;

    const int tid  = threadIdx.x;
    const int lane = tid & 63;
    const int wave = tid >> 6;
    const int wm = wave >> 1, wn = wave & 1;

    __shared__ __align__(16) _Float16 As[128 * 64];
    __shared__ __align__(16) _Float16 Bs[128 * 64];

    const int fr = lane & 15;
    const int kc = lane >> 4;

    floatx4 acc[4][4] = {};

    const int lrow   = lane >> 3;
    const int gchunk = ((lane & 7) ^ lrow) * 8;
    const _Float16* aS[4];
    const _Float16* bS[4];
    _Float16* aD[4];
    _Float16* bD[4];
#pragma unroll
    for (int i = 0; i < 4; ++i) {
        int rr = wave * 32 + i * 8;
        int ar = rowBase + rr + lrow; if (ar > M - 1) ar = M - 1;
        aS[i] = A  + (size_t)ar * K + gchunk;
        bS[i] = Bt + (size_t)(colBase + rr + lrow) * K + gchunk;
        aD[i] = As + rr * 64;
        bD[i] = Bs + rr * 64;
    }

    const int cp0 = ((kc)     ^ (fr & 7)) * 8;
    const int cp1 = ((4 + kc) ^ (fr & 7)) * 8;
    const int aro = (wm * 64 + fr) * 64;
    const int bro = (wn * 64 + fr) * 64;

    for (int kb = 0; kb < K; kb += 64) {
#pragma unroll
        for (int i = 0; i < 4; ++i) {
            GLOAD16(aS[i] + kb, aD[i]);
            GLOAD16(bS[i] + kb, bD[i]);
        }
        __syncthreads();

#pragma unroll
        for (int kks = 0; kks < 2; ++kks) {
            const int cp = kks ? cp1 : cp0;
            half8 afr[4], bfr[4];
#pragma unroll
            for (int mi = 0; mi < 4; ++mi)
                afr[mi] = *(const half8*)&As[aro + mi * 1024 + cp];
#pragma unroll
            for (int ni = 0; ni < 4; ++ni)
                bfr[ni] = *(const half8*)&Bs[bro + ni * 1024 + cp];
#pragma unroll
            for (int mi = 0; mi < 4; ++mi)
#pragma unroll
                for (int ni = 0; ni < 4; ++ni)
                    acc[mi][ni] = __builtin_amdgcn_mfma_f32_16x16x32_f16(
                        afr[mi], bfr[ni], acc[mi][ni], 0, 0, 0);
        }
        __syncthreads();
    }

    // ---- C write (f16) ----
#pragma unroll
    for (int mi = 0; mi < 4; ++mi) {
#pragma unroll
        for (int ni = 0; ni < 4; ++ni) {
            int col = colBase + wn * 64 + ni * 16 + fr;
#pragma unroll
            for (int j = 0; j < 4; ++j) {
                int row = rowBase + wm * 64 + mi * 16 + kc * 4 + j;
                if (row < M) C[(size_t)row * HID + col] = (_Float16)acc[mi][ni][j];
            }
        }
    }

    // ---- fused attention dots from f32 acc ----
    float as_c[4], ad_c[4];
#pragma unroll
    for (int ni = 0; ni < 4; ++ni) {
        int col = colBase + wn * 64 + ni * 16 + fr;
        as_c[ni] = att_s[col];
        ad_c[ni] = att_d[col];
    }
#pragma unroll
    for (int mi = 0; mi < 4; ++mi) {
#pragma unroll
        for (int j = 0; j < 4; ++j) {
            float ps = acc[mi][0][j] * as_c[0] + acc[mi][1][j] * as_c[1]
                     + acc[mi][2][j] * as_c[2] + acc[mi][3][j] * as_c[3];
            float pd = acc[mi][0][j] * ad_c[0] + acc[mi][1][j] * ad_c[1]
                     + acc[mi][2][j] * ad_c[2] + acc[mi][3][j] * ad_c[3];
#pragma unroll
            for (int mk = 1; mk < 16; mk <<= 1) {
                ps += __shfl_xor(ps, mk);
                pd += __shfl_xor(pd, mk);
            }
            if (fr == 0) {
                int row = rowBase + wm * 64 + mi * 16 + kc * 4 + j;
                if (row < M) {
                    atomicAdd(a_s + row, ps);
                    atomicAdd(a_d + row, pd);
                }
            }
        }
    }
}

// ================= CSR build (once per call) =================
__global__ void count_kernel(const int* __restrict__ dst, int* __restrict__ cnt) {
    int i = blockIdx.x * blockDim.x + threadIdx.x;
    if (i < N_EDGES) atomicAdd(cnt + dst[i], 1);
}

__global__ __launch_bounds__(SCAN_BLK) void scan1_kernel(const int* __restrict__ cnt,
                                                         int* __restrict__ partial,
                                                         int* __restrict__ blocksum) {
    __shared__ int tmp[SCAN_BLK];
    int t = threadIdx.x;
    int i = blockIdx.x * SCAN_BLK + t;
    int v = (i < N_NODES) ? cnt[i] : 0;
    tmp[t] = v;
    __syncthreads();
    for (int off = 1; off < SCAN_BLK; off <<= 1) {
        int u = (t >= off) ? tmp[t - off] : 0;
        __syncthreads();
        tmp[t] += u;
        __syncthreads();
    }
    if (i < N_NODES) partial[i] = tmp[t] - v;
    if (t == SCAN_BLK - 1) blocksum[blockIdx.x] = tmp[t];
}

__global__ __launch_bounds__(SCAN_BLK) void scan2_kernel(int* __restrict__ blocksum) {
    __shared__ int tmp[SCAN_BLK];
    int t = threadIdx.x;
    int v = (t < N_SCAN_BLOCKS) ? blocksum[t] : 0;
    tmp[t] = v;
    __syncthreads();
    for (int off = 1; off < SCAN_BLK; off <<= 1) {
        int u = (t >= off) ? tmp[t - off] : 0;
        __syncthreads();
        tmp[t] += u;
        __syncthreads();
    }
    if (t < N_SCAN_BLOCKS) blocksum[t] = tmp[t] - v;
}

__global__ __launch_bounds__(SCAN_BLK) void scan3_kernel(const int* __restrict__ partial,
                                                         const int* __restrict__ blocksum,
                                                         int* __restrict__ rowptr,
                                                         int* __restrict__ cursor) {
    int i = blockIdx.x * SCAN_BLK + threadIdx.x;
    if (i < N_NODES) {
        int r = partial[i] + blocksum[blockIdx.x];
        rowptr[i] = r;
        cursor[i] = r;
    }
    if (i == 0) rowptr[N_NODES] = N_EDGES;
}

__global__ void scatter_kernel(const int* __restrict__ src, const int* __restrict__ dst,
                               int* __restrict__ cursor, int* __restrict__ src_s) {
    int i = blockIdx.x * blockDim.x + threadIdx.x;
    if (i >= N_EDGES) return;
    int p = atomicAdd(cursor + dst[i], 1);
    src_s[p] = src[i];
}

// ========== wave-parallel segment softmax: alpha[E] (16-lane group per dst) ==========
__global__ __launch_bounds__(256) void alpha_kernel(const int* __restrict__ rowptr,
                                                    const int* __restrict__ src_s,
                                                    const float* __restrict__ a_s,
                                                    const float* __restrict__ a_d,
                                                    float* __restrict__ alpha) {
    const int grp = threadIdx.x >> 4;
    const int l16 = threadIdx.x & 15;
    const int n = blockIdx.x * 16 + grp;
    if (n >= N_NODES) return;
    const int beg = rowptr[n], end = rowptr[n + 1];
    const float a_dn = a_d[n];

    float vmax = -__builtin_inff();
    for (int j = beg + l16; j < end; j += 16) {
        float v = a_s[src_s[j]] + a_dn;
        v = v > 0.f ? v : NEG_SLOPE * v;
        alpha[j] = v;
        vmax = fmaxf(vmax, v);
    }
#pragma unroll
    for (int m = 1; m < 16; m <<= 1) vmax = fmaxf(vmax, __shfl_xor(vmax, m));

    float psum = 0.f;
    for (int j = beg + l16; j < end; j += 16) {
        float p = __expf(alpha[j] - vmax);
        alpha[j] = p;
        psum += p;
    }
#pragma unroll
    for (int m = 1; m < 16; m <<= 1) psum += __shfl_xor(psum, m);

    const float inv = 1.f / (psum + 1e-16f);
    for (int j = beg + l16; j < end; j += 16) alpha[j] *= inv;
}

// ========== pure weighted gather (unroll-4): out[n] = sum alpha_j h[src_j] + bias ==========
__global__ __launch_bounds__(256) void aggregate2(const int* __restrict__ rowptr,
                                                  const int* __restrict__ src_s,
                                                  const float* __restrict__ alpha,
                                                  const _Float16* __restrict__ h,
                                                  const float* __restrict__ bias,
                                                  int do_relu,
                                                  _Float16* __restrict__ outx) {
    int wave = threadIdx.x >> 6;
    int lane = threadIdx.x & 63;
    int n = blockIdx.x * 4 + wave;
    if (n >= N_NODES) return;
    const int beg = rowptr[n], end = rowptr[n + 1];
    float acc[8] = {};
    int j = beg;
    for (; j + 3 < end; j += 4) {                 // 4 independent 16B loads in flight
        int s0 = src_s[j], s1 = src_s[j + 1], s2 = src_s[j + 2], s3 = src_s[j + 3];
        float al0 = alpha[j], al1 = alpha[j + 1], al2 = alpha[j + 2], al3 = alpha[j + 3];
        half8 hv0 = *(const half8*)(h + (size_t)s0 * HID + lane * 8);
        half8 hv1 = *(const half8*)(h + (size_t)s1 * HID + lane * 8);
        half8 hv2 = *(const half8*)(h + (size_t)s2 * HID + lane * 8);
        half8 hv3 = *(const half8*)(h + (size_t)s3 * HID + lane * 8);
#pragma unroll
        for (int qq = 0; qq < 8; ++qq) acc[qq] = fmaf(al0, (float)hv0[qq], acc[qq]);
#pragma unroll
        for (int qq = 0; qq < 8; ++qq) acc[qq] = fmaf(al1, (float)hv1[qq], acc[qq]);
#pragma unroll
        for (int qq = 0; qq < 8; ++qq) acc[qq] = fmaf(al2, (float)hv2[qq], acc[qq]);
#pragma unroll
        for (int qq = 0; qq < 8; ++qq) acc[qq] = fmaf(al3, (float)hv3[qq], acc[qq]);
    }
    for (; j < end; ++j) {
        int s0 = src_s[j];
        float al0 = alpha[j];
        half8 hv0 = *(const half8*)(h + (size_t)s0 * HID + lane * 8);
#pragma unroll
        for (int qq = 0; qq < 8; ++qq) acc[qq] = fmaf(al0, (float)hv0[qq], acc[qq]);
    }
    const float4 b0 = ((const float4*)(bias + lane * 8))[0];
    const float4 b1 = ((const float4*)(bias + lane * 8))[1];
    float o[8];
    o[0] = acc[0] + b0.x; o[1] = acc[1] + b0.y;
    o[2] = acc[2] + b0.z; o[3] = acc[3] + b0.w;
    o[4] = acc[4] + b1.x; o[5] = acc[5] + b1.y;
    o[6] = acc[6] + b1.z; o[7] = acc[7] + b1.w;
    half8 ov;
#pragma unroll
    for (int qq = 0; qq < 8; ++qq) {
        float val = do_relu ? fmaxf(o[qq], 0.f) : o[qq];
        ov[qq] = (_Float16)val;
    }
    *(half8*)(outx + (size_t)n * HID + lane * 8) = ov;
}

// ========== atomic-free global max pool over f16 activations (batch sorted) ==========
__global__ __launch_bounds__(128) void pool1_kernel(const _Float16* __restrict__ X,
                                                    const int* __restrict__ batch,
                                                    float* __restrict__ partial) {
    const int t = threadIdx.x;
    const int b = blockIdx.x;
    const int n0 = b * POOL_STRIP;
    const int n1 = min(n0 + POOL_STRIP, N_NODES);
    const float NEG = -__builtin_inff();
    const float4 neg4 = make_float4(NEG, NEG, NEG, NEG);
#pragma unroll
    for (int g = 0; g < N_GRAPHS; ++g)
        ((float4*)(partial + ((size_t)b * N_GRAPHS + g) * HID))[t] = neg4;
    int gcur = batch[n0];
    float4 m = neg4;
    for (int n = n0; n < n1; ++n) {
        int g = batch[n];
        if (g != gcur) {
            ((float4*)(partial + ((size_t)b * N_GRAPHS + gcur) * HID))[t] = m;
            m = neg4;
            gcur = g;
        }
        half4 hv = *(const half4*)(X + (size_t)n * HID + t * 4);
        m.x = fmaxf(m.x, (float)hv[0]); m.y = fmaxf(m.y, (float)hv[1]);
        m.z = fmaxf(m.z, (float)hv[2]); m.w = fmaxf(m.w, (float)hv[3]);
    }
    ((float4*)(partial + ((size_t)b * N_GRAPHS + gcur) * HID))[t] = m;
}

__global__ __launch_bounds__(128) void pool2_kernel(const float* __restrict__ partial,
                                                    float* __restrict__ pooled) {
    const int g = blockIdx.x;
    const int t = threadIdx.x;
    const float NEG = -__builtin_inff();
    float4 m = make_float4(NEG, NEG, NEG, NEG);
    for (int b = 0; b < POOL_NBLOCKS; ++b) {
        float4 v = ((const float4*)(partial + ((size_t)b * N_GRAPHS + g) * HID))[t];
        m.x = fmaxf(m.x, v.x); m.y = fmaxf(m.y, v.y);
        m.z = fmaxf(m.z, v.z); m.w = fmaxf(m.w, v.w);
    }
    ((float4*)(pooled + (size_t)g * HID))[t] = m;
}

// ---------- final tiny linear ----------
__global__ __launch_bounds__(64) void final_linear_kernel(const float* __restrict__ pooled,
                                                          const float* __restrict__ Wlin,
                                                          const float* __restrict__ blin,
                                                          float* __restrict__ out) {
    int t = threadIdx.x;
    if (t >= N_GRAPHS * N_CLASSES) return;
    int g = t / N_CLASSES, c = t % N_CLASSES;
    float s = blin[c];
    for (int k = 0; k < HID; ++k)
        s = fmaf(pooled[(size_t)g * HID + k], Wlin[(size_t)k * N_CLASSES + c], s);
    out[t] = s;
}

// ---------- launch ----------
extern "C" void kernel_launch(void* const* d_in, const int* in_sizes, int n_in,
                              void* d_out, int out_size, void* d_ws, size_t ws_size,
                              hipStream_t stream) {
    const float* x       = (const float*)d_in[0];
    const int*   eidx    = (const int*)d_in[1];
    const int*   batch   = (const int*)d_in[2];
    const float* W[3]    = {(const float*)d_in[3], (const float*)d_in[7], (const float*)d_in[11]};
    const float* Asrc[3] = {(const float*)d_in[4], (const float*)d_in[8], (const float*)d_in[12]};
    const float* Adst[3] = {(const float*)d_in[5], (const float*)d_in[9], (const float*)d_in[13]};
    const float* Bias[3] = {(const float*)d_in[6], (const float*)d_in[10], (const float*)d_in[14]};
    const float* Wlin    = (const float*)d_in[15];
    const float* blin    = (const float*)d_in[16];
    const int* src = eidx;
    const int* dst = eidx + N_EDGES;

    // ---- workspace layout (4-byte words) ----
    float* wsf    = (float*)d_ws;
    _Float16* x16 = (_Float16*)wsf;                              // words [0, 25.6M)
    float* ealpha = wsf + 24800000;                              // [E] f32, in dead x16 tail
    _Float16* hH  = (_Float16*)(wsf + 25600000);                 // 12.8M words
    _Float16* xAct= (_Float16*)(wsf + 25600000 + 12800000);      // 12.8M words
    float* a_s    = wsf + 25600000 + 12800000 + 12800000;        // [N]
    float* a_d    = a_s + N_NODES;                               // [N] (contiguous with a_s)
    float* pooled = a_d + N_NODES;                               // [8,512]
    int* cnt      = (int*)(pooled + N_GRAPHS * HID);             // [N]
    int* rowptr   = cnt + N_NODES;                               // [N+1]
    int* cursor   = rowptr + N_NODES + 1;                        // [N]
    int* partial  = cursor + N_NODES;                            // [N]
    int* blocksum = partial + N_NODES;                           // [256]
    int* src_s    = blocksum + 256;                              // [E]
    _Float16* Wt1 = (_Float16*)(src_s + N_EDGES);                // [512][1024]
    _Float16* Wt2 = Wt1 + (size_t)HID * IN_DIM;                  // [512][512]
    _Float16* Wt3 = Wt2 + (size_t)HID * HID;                     // [512][512]
    _Float16* WtL[3] = {Wt1, Wt2, Wt3};

    int edge_blocks = (N_EDGES + 255) / 256;

    // ---- CSR build ----
    hipMemsetAsync(cnt, 0, N_NODES * sizeof(int), stream);
    count_kernel<<<edge_blocks, 256, 0, stream>>>(dst, cnt);
    scan1_kernel<<<N_SCAN_BLOCKS, SCAN_BLK, 0, stream>>>(cnt, partial, blocksum);
    scan2_kernel<<<1, SCAN_BLK, 0, stream>>>(blocksum);
    scan3_kernel<<<N_SCAN_BLOCKS, SCAN_BLK, 0, stream>>>(partial, blocksum, rowptr, cursor);
    scatter_kernel<<<edge_blocks, 256, 0, stream>>>(src, dst, cursor, src_s);

    // ---- one-time precasts ----
    cast_x_f16<<<2048, 256, 0, stream>>>(x, x16);
    dim3 tgrid(IN_DIM / 32, HID / 32, 3);
    transpose_cast_W3<<<tgrid, 256, 0, stream>>>(W[0], W[1], W[2], Wt1, Wt2, Wt3);

    // ---- 3 GAT layers ----
    const int nrow_tiles = (N_NODES + 127) / 128;     // 391
    const int gemm_blocks = nrow_tiles * (HID / 128); // 1564
    for (int l = 0; l < 3; ++l) {
        int K = (l == 0) ? IN_DIM : HID;
        const _Float16* Ain = (l == 0) ? x16 : xAct;
        hipMemsetAsync(a_s, 0, 2 * N_NODES * sizeof(float), stream);  // a_s + a_d
        gemm_mfma_f16<<<gemm_blocks, 256, 0, stream>>>(
            Ain, WtL[l], hH, Asrc[l], Adst[l], a_s, a_d, N_NODES, K);
        alpha_kernel<<<(N_NODES + 15) / 16, 256, 0, stream>>>(rowptr, src_s, a_s, a_d, ealpha);
        aggregate2<<<(N_NODES + 3) / 4, 256, 0, stream>>>(
            rowptr, src_s, ealpha, hH, Bias[l], (l < 2) ? 1 : 0, xAct);
    }

    // ---- pool + classifier ----
    float* pool_partial = (float*)x16;   // head of dead x16 region
    pool1_kernel<<<POOL_NBLOCKS, 128, 0, stream>>>(xAct, batch, pool_partial);
    pool2_kernel<<<N_GRAPHS, 128, 0, stream>>>(pool_partial, pooled);
    final_linear_kernel<<<1, 64, 0, stream>>>(pooled, Wlin, blin, (float*)d_out);
}

// Round 11
// 806.164 us; speedup vs baseline: 1.0587x; 1.0587x over previous
//
#include <hip/hip_runtime.h>
#include <cmath>

#define N_NODES 50000
#define N_EDGES 800000
#define IN_DIM 1024
#define HID 512
#define N_CLASSES 6
#define N_GRAPHS 8
#define NEG_SLOPE 0.2f
#define SCAN_BLK 256
#define N_SCAN_BLOCKS ((N_NODES + SCAN_BLK - 1) / SCAN_BLK)   // 196
#define POOL_STRIP 256
#define POOL_NBLOCKS ((N_NODES + POOL_STRIP - 1) / POOL_STRIP) // 196

typedef _Float16 half8 __attribute__((ext_vector_type(8)));
typedef _Float16 half4 __attribute__((ext_vector_type(4)));
typedef float floatx4 __attribute__((ext_vector_type(4)));

// ---------- async global->LDS, 16B per lane ----------
typedef const __attribute__((address_space(1))) void* gas_ptr;
typedef __attribute__((address_space(3))) void* las_ptr;
#define GLOAD16(gp, lp) \
    __builtin_amdgcn_global_load_lds((gas_ptr)(gp), (las_ptr)(lp), 16, 0, 0)

// ---------- all-3-layer W transpose + cast in one launch ----------
__global__ __launch_bounds__(256) void transpose_cast_W3(const float* __restrict__ W1,
                                                         const float* __restrict__ W2,
                                                         const float* __restrict__ W3,
                                                         _Float16* __restrict__ Wt1,
                                                         _Float16* __restrict__ Wt2,
                                                         _Float16* __restrict__ Wt3) {
    const int l = blockIdx.z;
    const float* W = (l == 0) ? W1 : (l == 1) ? W2 : W3;
    _Float16* Wt   = (l == 0) ? Wt1 : (l == 1) ? Wt2 : Wt3;
    const int K    = (l == 0) ? IN_DIM : HID;
    if (blockIdx.x * 32 >= K) return;
    __shared__ float sh[32][33];
    const int kb = blockIdx.x * 32, nb = blockIdx.y * 32;
    const int tx = threadIdx.x & 31, ty = threadIdx.x >> 5;
#pragma unroll
    for (int i = 0; i < 32; i += 8)
        sh[ty + i][tx] = W[(size_t)(kb + ty + i) * HID + nb + tx];
    __syncthreads();
#pragma unroll
    for (int i = 0; i < 32; i += 8)
        Wt[(size_t)(nb + ty + i) * K + kb + tx] = (_Float16)sh[tx][ty + i];
}

// ---------- MFMA GEMM: C[M,512](f16) = A[M,K] @ Bt[512,K]^T ----------
// 128x128 tile, 4 waves (2x2), BK=64, gload_lds + both-sides XOR swizzle.
// AT = _Float16: A staged as f16 (16 KB).  AT = float: A staged as f32 (32 KB),
// converted f32->f16 in registers after ds_read (same rounding as a precast).
template <typename AT>
__global__ __launch_bounds__(256) void gemm_mfma(const AT* __restrict__ A,
                                                 const _Float16* __restrict__ Bt,
                                                 _Float16* __restrict__ C,
                                                 int M, int K) {
    constexpr bool F32A = (sizeof(AT) == 4);
    // ---- bijective XCD swizzle (m204) ----
    const int nwg = gridDim.x;
    const int bid = blockIdx.x;
    const int q = nwg >> 3, r = nwg & 7;
    const int xcd = bid & 7, local = bid >> 3;
    const int wgid = (xcd < r) ? xcd * (q + 1) + local
                               : r * (q + 1) + (xcd - r) * q + local;
    const int rowBase = (wgid >> 2) * 128;
    const int colBase = (wgid & 3) * 128;

    const int tid  = threadIdx.x;
    const int lane = tid & 63;
    const int wave = tid >> 6;
    const int wm = wave >> 1, wn = wave & 1;

    __shared__ __align__(16) AT       As[128 * 64];   // f16: 16 KB, f32: 32 KB
    __shared__ __align__(16) _Float16 Bs[128 * 64];   // 16 KB

    const int fr = lane & 15;
    const int kc = lane >> 4;

    floatx4 acc[4][4] = {};

    // ---- staging descriptors ----
    constexpr int NA = F32A ? 8 : 4;     // A gload16s per wave
    const AT* aS[NA];
    AT*       aD[NA];
    const _Float16* bS[4];
    _Float16*       bD[4];
    if constexpr (F32A) {
        // 16B = 4 floats; row = 16 chunks of 16B; 4 rows per gload16.
        const int lrow = lane >> 4;                     // 0..3
#pragma unroll
        for (int i = 0; i < 8; ++i) {
            int rr = wave * 32 + i * 4;
            int rowt = rr + lrow;                       // row in tile
            int ch = (lane & 15) ^ (rowt & 15);         // pre-swizzled source chunk
            int ar = rowBase + rowt; if (ar > M - 1) ar = M - 1;
            aS[i] = A + (size_t)ar * K + ch * 4;
            aD[i] = As + rr * 64;
        }
    } else {
        // 16B = 8 f16; row = 8 chunks of 16B; 8 rows per gload16.
        const int lrow = lane >> 3;                     // 0..7
#pragma unroll
        for (int i = 0; i < 4; ++i) {
            int rr = wave * 32 + i * 8;
            int ch = (lane & 7) ^ ((rr + lrow) & 7);
            int ar = rowBase + rr + lrow; if (ar > M - 1) ar = M - 1;
            aS[i] = A + (size_t)ar * K + ch * 8;
            aD[i] = As + rr * 64;
        }
    }
    {
        const int lrow = lane >> 3;
#pragma unroll
        for (int i = 0; i < 4; ++i) {
            int rr = wave * 32 + i * 8;
            int ch = (lane & 7) ^ ((rr + lrow) & 7);
            bS[i] = Bt + (size_t)(colBase + rr + lrow) * K + ch * 8;
            bD[i] = Bs + rr * 64;
        }
    }

    // ---- fragment-read offsets ----
    const int aro = (wm * 64 + fr) * 64;                // A row offset (elems)
    const int bro = (wn * 64 + fr) * 64;
    const int bcp0 = ((kc)     ^ (fr & 7)) * 8;         // B chunk (f16 elems)
    const int bcp1 = ((4 + kc) ^ (fr & 7)) * 8;
    // f32 A: chunk = 4 floats; logical chunks {2kc,2kc+1} (+8 for kks=1), key=fr
    const int ac00 = ((2 * kc)     ^ fr) * 4;
    const int ac01 = ((2 * kc + 1) ^ fr) * 4;
    const int ac10 = ((8 + 2 * kc)     ^ fr) * 4;
    const int ac11 = ((8 + 2 * kc + 1) ^ fr) * 4;

    for (int kb = 0; kb < K; kb += 64) {
        if constexpr (F32A) {
#pragma unroll
            for (int i = 0; i < 8; ++i) GLOAD16(aS[i] + kb, aD[i]);
        } else {
#pragma unroll
            for (int i = 0; i < 4; ++i) GLOAD16(aS[i] + kb, aD[i]);
        }
#pragma unroll
        for (int i = 0; i < 4; ++i) GLOAD16(bS[i] + kb, bD[i]);
        __syncthreads();

#pragma unroll
        for (int kks = 0; kks < 2; ++kks) {
            half8 afr[4], bfr[4];
            if constexpr (F32A) {
                const int c0 = kks ? ac10 : ac00;
                const int c1 = kks ? ac11 : ac01;
#pragma unroll
                for (int mi = 0; mi < 4; ++mi) {
                    floatx4 f0 = *(const floatx4*)&As[aro + mi * 1024 + c0];
                    floatx4 f1 = *(const floatx4*)&As[aro + mi * 1024 + c1];
                    half8 h;
                    h[0] = (_Float16)f0[0]; h[1] = (_Float16)f0[1];
                    h[2] = (_Float16)f0[2]; h[3] = (_Float16)f0[3];
                    h[4] = (_Float16)f1[0]; h[5] = (_Float16)f1[1];
                    h[6] = (_Float16)f1[2]; h[7] = (_Float16)f1[3];
                    afr[mi] = h;
                }
            } else {
                const int cp = kks ? bcp1 : bcp0;   // same geometry as B
#pragma unroll
                for (int mi = 0; mi < 4; ++mi)
                    afr[mi] = *(const half8*)&((const _Float16*)As)[aro + mi * 1024 + cp];
            }
            const int bcp = kks ? bcp1 : bcp0;
#pragma unroll
            for (int ni = 0; ni < 4; ++ni)
                bfr[ni] = *(const half8*)&Bs[bro + ni * 1024 + bcp];
#pragma unroll
            for (int mi = 0; mi < 4; ++mi)
#pragma unroll
                for (int ni = 0; ni < 4; ++ni)
                    acc[mi][ni] = __builtin_amdgcn_mfma_f32_16x16x32_f16(
                        afr[mi], bfr[ni], acc[mi][ni], 0, 0, 0);
        }
        __syncthreads();
    }

    // ---- C write (f16): col = lane&15, row = (lane>>4)*4 + j ----
#pragma unroll
    for (int mi = 0; mi < 4; ++mi) {
#pragma unroll
        for (int ni = 0; ni < 4; ++ni) {
            int col = colBase + wn * 64 + ni * 16 + fr;
#pragma unroll
            for (int j = 0; j < 4; ++j) {
                int row = rowBase + wm * 64 + mi * 16 + kc * 4 + j;
                if (row < M) C[(size_t)row * HID + col] = (_Float16)acc[mi][ni][j];
            }
        }
    }
}

// ---------- per-node attention dots (h in fp16; one wave per node) ----------
__global__ __launch_bounds__(256) void adot_kernel(const _Float16* __restrict__ h,
                                                   const float* __restrict__ att_s,
                                                   const float* __restrict__ att_d,
                                                   float* __restrict__ a_s,
                                                   float* __restrict__ a_d) {
    int wave = threadIdx.x >> 6;
    int lane = threadIdx.x & 63;
    int n = blockIdx.x * 4 + wave;
    if (n >= N_NODES) return;
    half8 hv = *(const half8*)(h + (size_t)n * HID + lane * 8);
    float4 s0 = ((const float4*)att_s)[lane * 2];
    float4 s1 = ((const float4*)att_s)[lane * 2 + 1];
    float4 d0 = ((const float4*)att_d)[lane * 2];
    float4 d1 = ((const float4*)att_d)[lane * 2 + 1];
    float hf[8];
#pragma unroll
    for (int qq = 0; qq < 8; ++qq) hf[qq] = (float)hv[qq];
    float ss = hf[0]*s0.x + hf[1]*s0.y + hf[2]*s0.z + hf[3]*s0.w
             + hf[4]*s1.x + hf[5]*s1.y + hf[6]*s1.z + hf[7]*s1.w;
    float sd = hf[0]*d0.x + hf[1]*d0.y + hf[2]*d0.z + hf[3]*d0.w
             + hf[4]*d1.x + hf[5]*d1.y + hf[6]*d1.z + hf[7]*d1.w;
#pragma unroll
    for (int off = 32; off; off >>= 1) {
        ss += __shfl_down(ss, off);
        sd += __shfl_down(sd, off);
    }
    if (lane == 0) { a_s[n] = ss; a_d[n] = sd; }
}

// ================= CSR build (once per call) =================
__global__ void count_kernel(const int* __restrict__ dst, int* __restrict__ cnt) {
    int i = blockIdx.x * blockDim.x + threadIdx.x;
    if (i < N_EDGES) atomicAdd(cnt + dst[i], 1);
}

__global__ __launch_bounds__(SCAN_BLK) void scan1_kernel(const int* __restrict__ cnt,
                                                         int* __restrict__ partial,
                                                         int* __restrict__ blocksum) {
    __shared__ int tmp[SCAN_BLK];
    int t = threadIdx.x;
    int i = blockIdx.x * SCAN_BLK + t;
    int v = (i < N_NODES) ? cnt[i] : 0;
    tmp[t] = v;
    __syncthreads();
    for (int off = 1; off < SCAN_BLK; off <<= 1) {
        int u = (t >= off) ? tmp[t - off] : 0;
        __syncthreads();
        tmp[t] += u;
        __syncthreads();
    }
    if (i < N_NODES) partial[i] = tmp[t] - v;
    if (t == SCAN_BLK - 1) blocksum[blockIdx.x] = tmp[t];
}

__global__ __launch_bounds__(SCAN_BLK) void scan2_kernel(int* __restrict__ blocksum) {
    __shared__ int tmp[SCAN_BLK];
    int t = threadIdx.x;
    int v = (t < N_SCAN_BLOCKS) ? blocksum[t] : 0;
    tmp[t] = v;
    __syncthreads();
    for (int off = 1; off < SCAN_BLK; off <<= 1) {
        int u = (t >= off) ? tmp[t - off] : 0;
        __syncthreads();
        tmp[t] += u;
        __syncthreads();
    }
    if (t < N_SCAN_BLOCKS) blocksum[t] = tmp[t] - v;
}

__global__ __launch_bounds__(SCAN_BLK) void scan3_kernel(const int* __restrict__ partial,
                                                         const int* __restrict__ blocksum,
                                                         int* __restrict__ rowptr,
                                                         int* __restrict__ cursor) {
    int i = blockIdx.x * SCAN_BLK + threadIdx.x;
    if (i < N_NODES) {
        int r = partial[i] + blocksum[blockIdx.x];
        rowptr[i] = r;
        cursor[i] = r;
    }
    if (i == 0) rowptr[N_NODES] = N_EDGES;
}

__global__ void scatter_kernel(const int* __restrict__ src, const int* __restrict__ dst,
                               int* __restrict__ cursor, int* __restrict__ src_s) {
    int i = blockIdx.x * blockDim.x + threadIdx.x;
    if (i >= N_EDGES) return;
    int p = atomicAdd(cursor + dst[i], 1);
    src_s[p] = src[i];
}

// ========== wave-parallel segment softmax: alpha[E] (16-lane group per dst) ==========
__global__ __launch_bounds__(256) void alpha_kernel(const int* __restrict__ rowptr,
                                                    const int* __restrict__ src_s,
                                                    const float* __restrict__ a_s,
                                                    const float* __restrict__ a_d,
                                                    float* __restrict__ alpha) {
    const int grp = threadIdx.x >> 4;
    const int l16 = threadIdx.x & 15;
    const int n = blockIdx.x * 16 + grp;
    if (n >= N_NODES) return;
    const int beg = rowptr[n], end = rowptr[n + 1];
    const float a_dn = a_d[n];

    float vmax = -__builtin_inff();
    for (int j = beg + l16; j < end; j += 16) {
        float v = a_s[src_s[j]] + a_dn;
        v = v > 0.f ? v : NEG_SLOPE * v;
        alpha[j] = v;
        vmax = fmaxf(vmax, v);
    }
#pragma unroll
    for (int m = 1; m < 16; m <<= 1) vmax = fmaxf(vmax, __shfl_xor(vmax, m));

    float psum = 0.f;
    for (int j = beg + l16; j < end; j += 16) {
        float p = __expf(alpha[j] - vmax);
        alpha[j] = p;
        psum += p;
    }
#pragma unroll
    for (int m = 1; m < 16; m <<= 1) psum += __shfl_xor(psum, m);

    const float inv = 1.f / (psum + 1e-16f);
    for (int j = beg + l16; j < end; j += 16) alpha[j] *= inv;
}

// ========== pure weighted gather (unroll-4): out[n] = sum alpha_j h[src_j] + bias ==========
__global__ __launch_bounds__(256) void aggregate2(const int* __restrict__ rowptr,
                                                  const int* __restrict__ src_s,
                                                  const float* __restrict__ alpha,
                                                  const _Float16* __restrict__ h,
                                                  const float* __restrict__ bias,
                                                  int do_relu,
                                                  _Float16* __restrict__ outx) {
    int wave = threadIdx.x >> 6;
    int lane = threadIdx.x & 63;
    int n = blockIdx.x * 4 + wave;
    if (n >= N_NODES) return;
    const int beg = rowptr[n], end = rowptr[n + 1];
    float acc[8] = {};
    int j = beg;
    for (; j + 3 < end; j += 4) {
        int s0 = src_s[j], s1 = src_s[j + 1], s2 = src_s[j + 2], s3 = src_s[j + 3];
        float al0 = alpha[j], al1 = alpha[j + 1], al2 = alpha[j + 2], al3 = alpha[j + 3];
        half8 hv0 = *(const half8*)(h + (size_t)s0 * HID + lane * 8);
        half8 hv1 = *(const half8*)(h + (size_t)s1 * HID + lane * 8);
        half8 hv2 = *(const half8*)(h + (size_t)s2 * HID + lane * 8);
        half8 hv3 = *(const half8*)(h + (size_t)s3 * HID + lane * 8);
#pragma unroll
        for (int qq = 0; qq < 8; ++qq) acc[qq] = fmaf(al0, (float)hv0[qq], acc[qq]);
#pragma unroll
        for (int qq = 0; qq < 8; ++qq) acc[qq] = fmaf(al1, (float)hv1[qq], acc[qq]);
#pragma unroll
        for (int qq = 0; qq < 8; ++qq) acc[qq] = fmaf(al2, (float)hv2[qq], acc[qq]);
#pragma unroll
        for (int qq = 0; qq < 8; ++qq) acc[qq] = fmaf(al3, (float)hv3[qq], acc[qq]);
    }
    for (; j < end; ++j) {
        int s0 = src_s[j];
        float al0 = alpha[j];
        half8 hv0 = *(const half8*)(h + (size_t)s0 * HID + lane * 8);
#pragma unroll
        for (int qq = 0; qq < 8; ++qq) acc[qq] = fmaf(al0, (float)hv0[qq], acc[qq]);
    }
    const float4 b0 = ((const float4*)(bias + lane * 8))[0];
    const float4 b1 = ((const float4*)(bias + lane * 8))[1];
    float o[8];
    o[0] = acc[0] + b0.x; o[1] = acc[1] + b0.y;
    o[2] = acc[2] + b0.z; o[3] = acc[3] + b0.w;
    o[4] = acc[4] + b1.x; o[5] = acc[5] + b1.y;
    o[6] = acc[6] + b1.z; o[7] = acc[7] + b1.w;
    half8 ov;
#pragma unroll
    for (int qq = 0; qq < 8; ++qq) {
        float val = do_relu ? fmaxf(o[qq], 0.f) : o[qq];
        ov[qq] = (_Float16)val;
    }
    *(half8*)(outx + (size_t)n * HID + lane * 8) = ov;
}

// ========== atomic-free global max pool over f16 activations (batch sorted) ==========
__global__ __launch_bounds__(128) void pool1_kernel(const _Float16* __restrict__ X,
                                                    const int* __restrict__ batch,
                                                    float* __restrict__ partial) {
    const int t = threadIdx.x;
    const int b = blockIdx.x;
    const int n0 = b * POOL_STRIP;
    const int n1 = min(n0 + POOL_STRIP, N_NODES);
    const float NEG = -__builtin_inff();
    const float4 neg4 = make_float4(NEG, NEG, NEG, NEG);
#pragma unroll
    for (int g = 0; g < N_GRAPHS; ++g)
        ((float4*)(partial + ((size_t)b * N_GRAPHS + g) * HID))[t] = neg4;
    int gcur = batch[n0];
    float4 m = neg4;
    for (int n = n0; n < n1; ++n) {
        int g = batch[n];
        if (g != gcur) {
            ((float4*)(partial + ((size_t)b * N_GRAPHS + gcur) * HID))[t] = m;
            m = neg4;
            gcur = g;
        }
        half4 hv = *(const half4*)(X + (size_t)n * HID + t * 4);
        m.x = fmaxf(m.x, (float)hv[0]); m.y = fmaxf(m.y, (float)hv[1]);
        m.z = fmaxf(m.z, (float)hv[2]); m.w = fmaxf(m.w, (float)hv[3]);
    }
    ((float4*)(partial + ((size_t)b * N_GRAPHS + gcur) * HID))[t] = m;
}

__global__ __launch_bounds__(128) void pool2_kernel(const float* __restrict__ partial,
                                                    float* __restrict__ pooled) {
    const int g = blockIdx.x;
    const int t = threadIdx.x;
    const float NEG = -__builtin_inff();
    float4 m = make_float4(NEG, NEG, NEG, NEG);
    for (int b = 0; b < POOL_NBLOCKS; ++b) {
        float4 v = ((const float4*)(partial + ((size_t)b * N_GRAPHS + g) * HID))[t];
        m.x = fmaxf(m.x, v.x); m.y = fmaxf(m.y, v.y);
        m.z = fmaxf(m.z, v.z); m.w = fmaxf(m.w, v.w);
    }
    ((float4*)(pooled + (size_t)g * HID))[t] = m;
}

// ---------- final tiny linear ----------
__global__ __launch_bounds__(64) void final_linear_kernel(const float* __restrict__ pooled,
                                                          const float* __restrict__ Wlin,
                                                          const float* __restrict__ blin,
                                                          float* __restrict__ out) {
    int t = threadIdx.x;
    if (t >= N_GRAPHS * N_CLASSES) return;
    int g = t / N_CLASSES, c = t % N_CLASSES;
    float s = blin[c];
    for (int k = 0; k < HID; ++k)
        s = fmaf(pooled[(size_t)g * HID + k], Wlin[(size_t)k * N_CLASSES + c], s);
    out[t] = s;
}

// ---------- launch ----------
extern "C" void kernel_launch(void* const* d_in, const int* in_sizes, int n_in,
                              void* d_out, int out_size, void* d_ws, size_t ws_size,
                              hipStream_t stream) {
    const float* x       = (const float*)d_in[0];
    const int*   eidx    = (const int*)d_in[1];
    const int*   batch   = (const int*)d_in[2];
    const float* W[3]    = {(const float*)d_in[3], (const float*)d_in[7], (const float*)d_in[11]};
    const float* Asrc[3] = {(const float*)d_in[4], (const float*)d_in[8], (const float*)d_in[12]};
    const float* Adst[3] = {(const float*)d_in[5], (const float*)d_in[9], (const float*)d_in[13]};
    const float* Bias[3] = {(const float*)d_in[6], (const float*)d_in[10], (const float*)d_in[14]};
    const float* Wlin    = (const float*)d_in[15];
    const float* blin    = (const float*)d_in[16];
    const int* src = eidx;
    const int* dst = eidx + N_EDGES;

    // ---- workspace layout (4-byte words; region A no longer holds x16) ----
    float* wsf    = (float*)d_ws;
    float* ealpha = wsf + 24800000;                              // [E] f32
    _Float16* hH  = (_Float16*)(wsf + 25600000);                 // [N,512] f16
    _Float16* xAct= (_Float16*)(wsf + 25600000 + 12800000);      // [N,512] f16
    float* a_s    = wsf + 25600000 + 12800000 + 12800000;        // [N]
    float* a_d    = a_s + N_NODES;                               // [N]
    float* pooled = a_d + N_NODES;                               // [8,512]
    int* cnt      = (int*)(pooled + N_GRAPHS * HID);             // [N]
    int* rowptr   = cnt + N_NODES;                               // [N+1]
    int* cursor   = rowptr + N_NODES + 1;                        // [N]
    int* partial  = cursor + N_NODES;                            // [N]
    int* blocksum = partial + N_NODES;                           // [256]
    int* src_s    = blocksum + 256;                              // [E]
    _Float16* Wt1 = (_Float16*)(src_s + N_EDGES);                // [512][1024]
    _Float16* Wt2 = Wt1 + (size_t)HID * IN_DIM;                  // [512][512]
    _Float16* Wt3 = Wt2 + (size_t)HID * HID;                     // [512][512]

    int edge_blocks = (N_EDGES + 255) / 256;

    // ---- CSR build ----
    hipMemsetAsync(cnt, 0, N_NODES * sizeof(int), stream);
    count_kernel<<<edge_blocks, 256, 0, stream>>>(dst, cnt);
    scan1_kernel<<<N_SCAN_BLOCKS, SCAN_BLK, 0, stream>>>(cnt, partial, blocksum);
    scan2_kernel<<<1, SCAN_BLK, 0, stream>>>(blocksum);
    scan3_kernel<<<N_SCAN_BLOCKS, SCAN_BLK, 0, stream>>>(partial, blocksum, rowptr, cursor);
    scatter_kernel<<<edge_blocks, 256, 0, stream>>>(src, dst, cursor, src_s);

    // ---- one-time W precast ----
    dim3 tgrid(IN_DIM / 32, HID / 32, 3);
    transpose_cast_W3<<<tgrid, 256, 0, stream>>>(W[0], W[1], W[2], Wt1, Wt2, Wt3);

    // ---- 3 GAT layers ----
    const int nrow_tiles = (N_NODES + 127) / 128;     // 391
    const int gemm_blocks = nrow_tiles * (HID / 128); // 1564
    for (int l = 0; l < 3; ++l) {
        if (l == 0)
            gemm_mfma<float><<<gemm_blocks, 256, 0, stream>>>(x, Wt1, hH, N_NODES, IN_DIM);
        else
            gemm_mfma<_Float16><<<gemm_blocks, 256, 0, stream>>>(
                xAct, (l == 1) ? Wt2 : Wt3, hH, N_NODES, HID);
        adot_kernel<<<(N_NODES + 3) / 4, 256, 0, stream>>>(hH, Asrc[l], Adst[l], a_s, a_d);
        alpha_kernel<<<(N_NODES + 15) / 16, 256, 0, stream>>>(rowptr, src_s, a_s, a_d, ealpha);
        aggregate2<<<(N_NODES + 3) / 4, 256, 0, stream>>>(
            rowptr, src_s, ealpha, hH, Bias[l], (l < 2) ? 1 : 0, xAct);
    }

    // ---- pool + classifier ----
    float* pool_partial = wsf;   // head of free region
    pool1_kernel<<<POOL_NBLOCKS, 128, 0, stream>>>(xAct, batch, pool_partial);
    pool2_kernel<<<N_GRAPHS, 128, 0, stream>>>(pool_partial, pooled);
    final_linear_kernel<<<1, 64, 0, stream>>>(pooled, Wlin, blin, (float*)d_out);
}